// Round 15
// baseline (244.398 us; speedup 1.0000x reference)
//
#include <hip/hip_runtime.h>
#include <hip/hip_bf16.h>

typedef __attribute__((ext_vector_type(8))) short short8_t;
typedef __attribute__((ext_vector_type(4))) float f32x4;
typedef float f32x4u __attribute__((ext_vector_type(4), aligned(4)));  // 4B-aligned vector load

#define NNODES 50000
#define FIN 1433
#define HID 128
#define NCLS 7
#define KT1 45          // ceil(1433/32)
#define BK 32
#define BM 128
#define CAP 96          // fixed CSR slots/node; Poisson(32) => P(deg>96) ~ 0; exact via ovf
#define GSTR 1040       // A LDS g-stride in ushorts (128*8 + 16 pad -> conflict-free)

static __device__ __forceinline__ unsigned short f2bf(float f) {
    union { float f; unsigned int u; } v; v.f = f;
    unsigned int u = v.u;
    u += 0x7FFFu + ((u >> 16) & 1u);   // round-to-nearest-even
    return (unsigned short)(u >> 16);
}
static __device__ __forceinline__ float u2f(unsigned int u) {
    union { unsigned int u; float f; } v; v.u = u; return v.f;
}

// ---------------- W1 pack: W1[FIN][HID] f32 -> W1s[KT1][512 segs][8 bf16]
__global__ void prep_w1(const float* __restrict__ W1, unsigned short* __restrict__ W1s) {
    int tid = blockIdx.x * 512 + threadIdx.x;
    if (tid >= KT1 * 512) return;
    int kt = tid >> 9, seg = tid & 511;
    int c = seg & 127, g = seg >> 7;
    int kb = kt * BK + g * 8;
    unsigned int w[4];
    #pragma unroll
    for (int p = 0; p < 4; ++p) {
        int k0 = kb + p * 2, k1 = kb + p * 2 + 1;
        unsigned short lo = (k0 < FIN) ? f2bf(W1[(size_t)k0 * HID + c]) : (unsigned short)0;
        unsigned short hi = (k1 < FIN) ? f2bf(W1[(size_t)k1 * HID + c]) : (unsigned short)0;
        w[p] = (unsigned int)lo | ((unsigned int)hi << 16);
    }
    uint4* dstp = (uint4*)(W1s + (size_t)tid * 8);
    uint4 val; val.x = w[0]; val.y = w[1]; val.z = w[2]; val.w = w[3];
    *dstp = val;
}

// ---------------- FAT kernel: gemm blocks [0,gb) || FILL blocks [gb, grid) ---
// GEMM: BM=128, BK=32, 512t. LDS 41KB -> 3 blocks/CU; launch_bounds(512,6)
// (VGPR cap ~84 -> NO SPILL, unlike (512,8)'s 48-reg cap). Counted vmcnt(3).
// FILL: fixed-stride CSR scatter (no counts/scan needed).
__global__ __launch_bounds__(512, 6) void gemm_fill(const float* __restrict__ x,
                                                    const unsigned short* __restrict__ W1s,
                                                    unsigned short* __restrict__ h, int M,
                                                    const int* __restrict__ src,
                                                    const int* __restrict__ dst, int E,
                                                    int* __restrict__ cnt,
                                                    int* __restrict__ csr_f,
                                                    int* __restrict__ ovf_cnt,
                                                    int2* __restrict__ ovf, int gb) {
    __shared__ unsigned short As[2][4160];   // [g^(row&3)][row][8], GSTR=1040
    __shared__ unsigned short Bs[3][4096];   // [g 4][c 128][8] linear (gload_lds)

    if (blockIdx.x >= gb) {
        // ---- fill blocks: 512 threads x 8 edges ----
        int bid = blockIdx.x - gb;
        int i = (bid * 512 + (int)threadIdx.x) * 8;
        int lim = min(i + 8, E);
        for (int e = i; e < lim; ++e) {
            int d = dst[e], s = src[e];
            int pos = atomicAdd(&cnt[d], 1);
            if (pos < CAP) csr_f[d * CAP + pos] = s;
            else { int op = atomicAdd(ovf_cnt, 1); ovf[op] = make_int2(d, s); }
        }
        return;
    }

    // ---- gemm blocks ----
    const int t = threadIdx.x;
    const int wave = t >> 6, lane = t & 63;
    const int wm = wave >> 1, wn = wave & 1;
    const int r = lane & 15, u = lane >> 4;       // u in 0..3 = K-octet & row-quad
    const int rowBase = blockIdx.x * BM;
    f32x4 acc[2][4] = {};

    float4 areg[2];

    auto issueA = [&](int kt) {
        int k0 = kt * BK;
        #pragma unroll
        for (int i = 0; i < 2; ++i) {
            int quad = i * 512 + t;
            int row = quad >> 3, kq = quad & 7;
            int gr = min(rowBase + row, M - 1);   // clamp; OOB rows unstored
            int gk = k0 + kq * 4;                 // in-bounds for kt <= 43
            f32x4u v = *(const f32x4u*)(x + (size_t)gr * FIN + gk);
            areg[i].x = v.x; areg[i].y = v.y; areg[i].z = v.z; areg[i].w = v.w;
        }
    };
    auto issueA_tail = [&]() {                    // kt=44: k 1408..1439, guard FIN
        #pragma unroll
        for (int i = 0; i < 2; ++i) {
            int quad = i * 512 + t;
            int row = quad >> 3, kq = quad & 7;
            int gr = min(rowBase + row, M - 1);
            int gk = 1408 + kq * 4;
            const float* p = x + (size_t)gr * FIN;
            areg[i].x = (gk + 0 < FIN) ? p[gk + 0] : 0.f;
            areg[i].y = (gk + 1 < FIN) ? p[gk + 1] : 0.f;
            areg[i].z = (gk + 2 < FIN) ? p[gk + 2] : 0.f;
            areg[i].w = (gk + 3 < FIN) ? p[gk + 3] : 0.f;
        }
    };
    auto issueB = [&](int kt, int buf) {
        const unsigned short* gp = W1s + ((size_t)kt * 512 + t) * 8;
        unsigned short* lp = &Bs[buf][(wave * 64) * 8];
        __builtin_amdgcn_global_load_lds(
            (const __attribute__((address_space(1))) unsigned int*)gp,
            (__attribute__((address_space(3))) unsigned int*)lp, 16, 0, 0);
    };
    auto writeA = [&](int buf) {
        #pragma unroll
        for (int i = 0; i < 2; ++i) {
            int quad = i * 512 + t;
            int row = quad >> 3, kq = quad & 7;
            __hip_bfloat162 lo2 = __float22bfloat162_rn(make_float2(areg[i].x, areg[i].y));
            __hip_bfloat162 hi2 = __float22bfloat162_rn(make_float2(areg[i].z, areg[i].w));
            unsigned int ulo, uhi;
            __builtin_memcpy(&ulo, &lo2, 4);
            __builtin_memcpy(&uhi, &hi2, 4);
            unsigned long long pk = ((unsigned long long)uhi << 32) | (unsigned long long)ulo;
            int g = kq >> 1, half = kq & 1;
            int us = ((g ^ (row & 3)) * GSTR) + row * 8 + half * 4;
            *(unsigned long long*)(&As[buf][us]) = pk;
        }
    };
    auto compute = [&](int kt) {
        const int abuf = kt & 1, bbuf = kt % 3;
        short8_t af[2], bfr[4];
        #pragma unroll
        for (int mi = 0; mi < 2; ++mi) {
            int row = wm * 32 + mi * 16 + r;
            int us = ((u ^ (row & 3)) * GSTR) + row * 8;
            af[mi] = *(const short8_t*)(&As[abuf][us]);
        }
        #pragma unroll
        for (int ni = 0; ni < 4; ++ni) {
            int c = wn * 64 + ni * 16 + r;
            bfr[ni] = *(const short8_t*)(&Bs[bbuf][u * 1024 + c * 8]);
        }
        #pragma unroll
        for (int mi = 0; mi < 2; ++mi)
            #pragma unroll
            for (int ni = 0; ni < 4; ++ni)
                acc[mi][ni] = __builtin_amdgcn_mfma_f32_16x16x32_bf16(af[mi], bfr[ni], acc[mi][ni], 0, 0, 0);
    };

    // prologue: tile 0 staged; tile 1 in flight
    issueA(0); issueB(0, 0);
    writeA(0);                       // implicit wait on A(0)
    issueA(1); issueB(1, 1);
    asm volatile("s_waitcnt vmcnt(3) lgkmcnt(0)" ::: "memory");  // retire B(0)
    __builtin_amdgcn_sched_barrier(0);
    __builtin_amdgcn_s_barrier();
    __builtin_amdgcn_sched_barrier(0);

    // main loop: kt = 0..41 (issues up to tile 43; tiles 0..43 all k-in-bounds)
    for (int kt = 0; kt < KT1 - 3; ++kt) {
        compute(kt);
        writeA((kt + 1) & 1);        // waits A(t+1)
        issueA(kt + 2);
        issueB(kt + 2, (kt + 2) % 3);
        // outstanding: B(t+1)1 + A(t+2)2 + B(t+2)1 = 4 -> retire B(t+1)
        asm volatile("s_waitcnt vmcnt(3) lgkmcnt(0)" ::: "memory");
        __builtin_amdgcn_sched_barrier(0);
        __builtin_amdgcn_s_barrier();
        __builtin_amdgcn_sched_barrier(0);
    }
    // kt = 42: last counted iter's compute+write; then leave counted regime
    {
        compute(KT1 - 3);            // 42
        writeA((KT1 - 2) & 1);       // A(43) -> As[1]
        __syncthreads();
    }
    // stage guarded tail tile 44 (outside counted regime)
    issueA_tail();
    issueB(KT1 - 1, (KT1 - 1) % 3);  // B(44) -> Bs[2]
    writeA((KT1 - 1) & 1);           // A(44) -> As[0]
    __syncthreads();
    compute(KT1 - 2);                // 43
    compute(KT1 - 1);                // 44

    // epilogue: C layout col=lane&15, row=(lane>>4)*4+reg (raw, no dinv)
    #pragma unroll
    for (int mi = 0; mi < 2; ++mi) {
        #pragma unroll
        for (int reg = 0; reg < 4; ++reg) {
            int grow = rowBase + wm * 32 + mi * 16 + u * 4 + reg;
            if (grow < M) {
                #pragma unroll
                for (int ni = 0; ni < 4; ++ni) {
                    int gcol = wn * 64 + ni * 16 + r;
                    h[(size_t)grow * HID + gcol] = f2bf(acc[mi][ni][reg]);
                }
            }
        }
    }
}

// ---------------- self-loop insert + dinv (one thread per node) --------------
__global__ void self_dinv(int* __restrict__ cnt, int* __restrict__ csr_f,
                          float* __restrict__ dinv,
                          int* __restrict__ ovf_cnt, int2* __restrict__ ovf, int n) {
    int i = blockIdx.x * 256 + threadIdx.x;
    if (i >= n) return;
    int c = cnt[i];
    if (c < CAP) csr_f[i * CAP + c] = i;
    else { int op = atomicAdd(ovf_cnt, 1); ovf[op] = make_int2(i, i); }
    cnt[i] = c + 1;
    dinv[i] = rsqrtf((float)(c + 1));
}

// ---------------- Aggregation 1 + bias + relu + @W2 fused ----------------
__global__ __launch_bounds__(256) void agg1(const unsigned short* __restrict__ h,
                                            const int* __restrict__ cnt,
                                            const int* __restrict__ csr_f,
                                            const float* __restrict__ dinv,
                                            const float* __restrict__ b1,
                                            const float* __restrict__ W2,
                                            const int* __restrict__ ovf_cnt,
                                            const int2* __restrict__ ovf,
                                            float* __restrict__ h2s, int n) {
    __shared__ float W2s[HID * NCLS];
    for (int i = threadIdx.x; i < HID * NCLS; i += 256) W2s[i] = W2[i];
    __syncthreads();
    int wave = threadIdx.x >> 6, lane = threadIdx.x & 63;
    int v = blockIdx.x * 4 + wave;
    if (v >= n) return;
    const int fr = lane & 15, g = lane >> 4;
    int total = cnt[v];
    int inrow = min(total, CAP);
    const int base = v * CAP;
    float acc[8] = {};
    #pragma unroll 4
    for (int j = g; j < inrow; j += 4) {
        int s = csr_f[base + j];
        float ds = dinv[s];
        uint4 q = *(const uint4*)(h + (size_t)s * HID + fr * 8);
        unsigned int w[4] = {q.x, q.y, q.z, q.w};
        #pragma unroll
        for (int p = 0; p < 4; ++p) {
            acc[p * 2 + 0] += ds * u2f(w[p] << 16);          // low bf16
            acc[p * 2 + 1] += ds * u2f(w[p] & 0xffff0000u);  // high bf16
        }
    }
    if (__builtin_expect(total > CAP, 0) && g == 0) {
        int on = *ovf_cnt;
        for (int k = 0; k < on; ++k) {
            int2 pr = ovf[k];
            if (pr.x == v) {
                int s = pr.y;
                float ds = dinv[s];
                uint4 q = *(const uint4*)(h + (size_t)s * HID + fr * 8);
                unsigned int w[4] = {q.x, q.y, q.z, q.w};
                #pragma unroll
                for (int p = 0; p < 4; ++p) {
                    acc[p * 2 + 0] += ds * u2f(w[p] << 16);
                    acc[p * 2 + 1] += ds * u2f(w[p] & 0xffff0000u);
                }
            }
        }
    }
    #pragma unroll
    for (int e = 0; e < 8; ++e) {
        acc[e] += __shfl_xor(acc[e], 16, 64);
        acc[e] += __shfl_xor(acc[e], 32, 64);
    }
    float dv = dinv[v];
    float p[NCLS];
    #pragma unroll
    for (int c = 0; c < NCLS; ++c) p[c] = 0.f;
    #pragma unroll
    for (int e = 0; e < 8; ++e) {
        int f = fr * 8 + e;
        float val = fmaxf(dv * acc[e] + b1[f], 0.f);
        #pragma unroll
        for (int c = 0; c < NCLS; ++c) p[c] += val * W2s[f * NCLS + c];
    }
    #pragma unroll
    for (int off = 8; off >= 1; off >>= 1)
        #pragma unroll
        for (int c = 0; c < NCLS; ++c)
            p[c] += __shfl_xor(p[c], off, 64);
    if (lane == 0) {
        #pragma unroll
        for (int c = 0; c < NCLS; ++c) h2s[(size_t)v * 8 + c] = dv * p[c];  // pre-scaled
        h2s[(size_t)v * 8 + 7] = 0.f;
    }
}

// ---------------- Aggregation 2 + bias ----------------
__global__ __launch_bounds__(256) void agg2(const float* __restrict__ h2s,
                                            const int* __restrict__ cnt,
                                            const int* __restrict__ csr_f,
                                            const float* __restrict__ dinv,
                                            const float* __restrict__ b2,
                                            const int* __restrict__ ovf_cnt,
                                            const int2* __restrict__ ovf,
                                            float* __restrict__ out, int n) {
    int wave = threadIdx.x >> 6, lane = threadIdx.x & 63;
    int half = lane >> 5;
    int c = lane & 7, g = (lane >> 3) & 3;
    int v = blockIdx.x * 8 + wave * 2 + half;
    if (v >= n) return;
    int total = cnt[v];
    int inrow = min(total, CAP);
    const int base = v * CAP;
    float acc = 0.f;
    #pragma unroll 4
    for (int j = g; j < inrow; j += 4) {
        int s = csr_f[base + j];
        acc += h2s[(size_t)s * 8 + c];
    }
    if (__builtin_expect(total > CAP, 0) && g == 0) {
        int on = *ovf_cnt;
        for (int k = 0; k < on; ++k) {
            int2 pr = ovf[k];
            if (pr.x == v) acc += h2s[(size_t)pr.y * 8 + c];
        }
    }
    acc += __shfl_xor(acc, 8, 64);
    acc += __shfl_xor(acc, 16, 64);
    if (g == 0 && c < NCLS) out[(size_t)v * NCLS + c] = dinv[v] * acc + b2[c];
}

extern "C" void kernel_launch(void* const* d_in, const int* in_sizes, int n_in,
                              void* d_out, int out_size, void* d_ws, size_t ws_size,
                              hipStream_t stream) {
    const float* x  = (const float*)d_in[0];
    const int*   ei = (const int*)d_in[1];    // int64 in reference but JAX x64-off => int32
    const float* W1 = (const float*)d_in[2];
    const float* b1 = (const float*)d_in[3];
    const float* W2 = (const float*)d_in[4];
    const float* b2 = (const float*)d_in[5];
    float* out = (float*)d_out;

    const int N = NNODES;
    const int E = in_sizes[1] / 2;
    const int* src = ei;
    const int* dst = ei + E;
    const int GB = (N + BM - 1) / BM;         // gemm blocks (391)
    const int FB = (E + 4095) / 4096;         // fill blocks (512t x 8 edges)

    char* ws = (char*)d_ws;
    size_t off = 0;
    auto alloc = [&](size_t bytes) {
        void* p = ws + off;
        off += (bytes + 255) & ~(size_t)255;
        return p;
    };
    int*   cnt     = (int*)alloc((size_t)N * 4);
    int*   ovf_cnt = (int*)alloc(4);
    float* dinv    = (float*)alloc((size_t)N * 4);
    int*   csr_f   = (int*)alloc((size_t)N * CAP * 4);
    int2*  ovf     = (int2*)alloc((size_t)4096 * 8);
    unsigned short* W1s = (unsigned short*)alloc((size_t)KT1 * 512 * 8 * 2);
    unsigned short* h   = (unsigned short*)alloc((size_t)N * HID * 2);
    float* h2s     = (float*)alloc((size_t)N * 8 * 4);

    // zero cnt + ovf_cnt (contiguous allocations)
    hipMemsetAsync(cnt, 0, ((char*)ovf_cnt - (char*)cnt) + 256, stream);
    prep_w1<<<(KT1 * 512 + 511) / 512, 512, 0, stream>>>(W1, W1s);
    gemm_fill<<<GB + FB, 512, 0, stream>>>(x, W1s, h, N, src, dst, E,
                                           cnt, csr_f, ovf_cnt, ovf, GB);
    self_dinv<<<(N + 255) / 256, 256, 0, stream>>>(cnt, csr_f, dinv, ovf_cnt, ovf, N);
    agg1<<<(N + 3) / 4, 256, 0, stream>>>(h, cnt, csr_f, dinv, b1, W2, ovf_cnt, ovf, h2s, N);
    agg2<<<(N + 7) / 8, 256, 0, stream>>>(h2s, cnt, csr_f, dinv, b2, ovf_cnt, ovf, out, N);
}

// Round 16
// 241.875 us; speedup vs baseline: 1.0104x; 1.0104x over previous
//
#include <hip/hip_runtime.h>
#include <hip/hip_bf16.h>

typedef __attribute__((ext_vector_type(8))) short short8_t;
typedef __attribute__((ext_vector_type(4))) float f32x4;
typedef float f32x4u __attribute__((ext_vector_type(4), aligned(4)));  // 4B-aligned vector load

#define NNODES 50000
#define FIN 1433
#define HID 128
#define NCLS 7
#define KT1 45          // ceil(1433/32)
#define BK 32
#define BM 128
#define CAP 96          // fixed CSR slots/node; Poisson(32) => P(deg>96) ~ 0; exact via ovf
#define GSTR 1040       // A LDS g-stride in ushorts (128*8 + 16 pad -> conflict-free)

static __device__ __forceinline__ unsigned short f2bf(float f) {
    union { float f; unsigned int u; } v; v.f = f;
    unsigned int u = v.u;
    u += 0x7FFFu + ((u >> 16) & 1u);   // round-to-nearest-even
    return (unsigned short)(u >> 16);
}
static __device__ __forceinline__ float u2f(unsigned int u) {
    union { unsigned int u; float f; } v; v.u = u; return v.f;
}

// ---------------- W1 pack: W1[FIN][HID] f32 -> W1s[KT1][512 segs][8 bf16]
__global__ void prep_w1(const float* __restrict__ W1, unsigned short* __restrict__ W1s) {
    int tid = blockIdx.x * 512 + threadIdx.x;
    if (tid >= KT1 * 512) return;
    int kt = tid >> 9, seg = tid & 511;
    int c = seg & 127, g = seg >> 7;
    int kb = kt * BK + g * 8;
    unsigned int w[4];
    #pragma unroll
    for (int p = 0; p < 4; ++p) {
        int k0 = kb + p * 2, k1 = kb + p * 2 + 1;
        unsigned short lo = (k0 < FIN) ? f2bf(W1[(size_t)k0 * HID + c]) : (unsigned short)0;
        unsigned short hi = (k1 < FIN) ? f2bf(W1[(size_t)k1 * HID + c]) : (unsigned short)0;
        w[p] = (unsigned int)lo | ((unsigned int)hi << 16);
    }
    uint4* dstp = (uint4*)(W1s + (size_t)tid * 8);
    uint4 val; val.x = w[0]; val.y = w[1]; val.z = w[2]; val.w = w[3];
    *dstp = val;
}

// ---------------- FAT kernel: gemm blocks [0,gb) || FILL blocks [gb, grid) ---
// GEMM: BM=128, BK=32, 512t. LDS 41KB; (512,4) -> compiler's natural ~68 VGPR
// (no spill), and 3 blocks/CU fit by BLOCK math: 3 x 2 waves/SIMD x 70 <= 512.
// Counted vmcnt(3) pipeline. FILL: fixed-stride CSR scatter.
__global__ __launch_bounds__(512, 4) void gemm_fill(const float* __restrict__ x,
                                                    const unsigned short* __restrict__ W1s,
                                                    unsigned short* __restrict__ h, int M,
                                                    const int* __restrict__ src,
                                                    const int* __restrict__ dst, int E,
                                                    int* __restrict__ cnt,
                                                    int* __restrict__ csr_f,
                                                    int* __restrict__ ovf_cnt,
                                                    int2* __restrict__ ovf, int gb) {
    __shared__ unsigned short As[2][4160];   // [g^(row&3)][row][8], GSTR=1040
    __shared__ unsigned short Bs[3][4096];   // [g 4][c 128][8] linear (gload_lds)

    if (blockIdx.x >= gb) {
        // ---- fill blocks: 512 threads x 8 edges ----
        int bid = blockIdx.x - gb;
        int i = (bid * 512 + (int)threadIdx.x) * 8;
        int lim = min(i + 8, E);
        for (int e = i; e < lim; ++e) {
            int d = dst[e], s = src[e];
            int pos = atomicAdd(&cnt[d], 1);
            if (pos < CAP) csr_f[d * CAP + pos] = s;
            else { int op = atomicAdd(ovf_cnt, 1); ovf[op] = make_int2(d, s); }
        }
        return;
    }

    // ---- gemm blocks ----
    const int t = threadIdx.x;
    const int wave = t >> 6, lane = t & 63;
    const int wm = wave >> 1, wn = wave & 1;
    const int r = lane & 15, u = lane >> 4;       // u in 0..3 = K-octet & row-quad
    const int rowBase = blockIdx.x * BM;
    f32x4 acc[2][4] = {};

    float4 areg[2];

    auto issueA = [&](int kt) {
        int k0 = kt * BK;
        #pragma unroll
        for (int i = 0; i < 2; ++i) {
            int quad = i * 512 + t;
            int row = quad >> 3, kq = quad & 7;
            int gr = min(rowBase + row, M - 1);   // clamp; OOB rows unstored
            int gk = k0 + kq * 4;                 // in-bounds for kt <= 43
            f32x4u v = *(const f32x4u*)(x + (size_t)gr * FIN + gk);
            areg[i].x = v.x; areg[i].y = v.y; areg[i].z = v.z; areg[i].w = v.w;
        }
    };
    auto issueA_tail = [&]() {                    // kt=44: k 1408..1439, guard FIN
        #pragma unroll
        for (int i = 0; i < 2; ++i) {
            int quad = i * 512 + t;
            int row = quad >> 3, kq = quad & 7;
            int gr = min(rowBase + row, M - 1);
            int gk = 1408 + kq * 4;
            const float* p = x + (size_t)gr * FIN;
            areg[i].x = (gk + 0 < FIN) ? p[gk + 0] : 0.f;
            areg[i].y = (gk + 1 < FIN) ? p[gk + 1] : 0.f;
            areg[i].z = (gk + 2 < FIN) ? p[gk + 2] : 0.f;
            areg[i].w = (gk + 3 < FIN) ? p[gk + 3] : 0.f;
        }
    };
    auto issueB = [&](int kt, int buf) {
        const unsigned short* gp = W1s + ((size_t)kt * 512 + t) * 8;
        unsigned short* lp = &Bs[buf][(wave * 64) * 8];
        __builtin_amdgcn_global_load_lds(
            (const __attribute__((address_space(1))) unsigned int*)gp,
            (__attribute__((address_space(3))) unsigned int*)lp, 16, 0, 0);
    };
    auto writeA = [&](int buf) {
        #pragma unroll
        for (int i = 0; i < 2; ++i) {
            int quad = i * 512 + t;
            int row = quad >> 3, kq = quad & 7;
            __hip_bfloat162 lo2 = __float22bfloat162_rn(make_float2(areg[i].x, areg[i].y));
            __hip_bfloat162 hi2 = __float22bfloat162_rn(make_float2(areg[i].z, areg[i].w));
            unsigned int ulo, uhi;
            __builtin_memcpy(&ulo, &lo2, 4);
            __builtin_memcpy(&uhi, &hi2, 4);
            unsigned long long pk = ((unsigned long long)uhi << 32) | (unsigned long long)ulo;
            int g = kq >> 1, half = kq & 1;
            int us = ((g ^ (row & 3)) * GSTR) + row * 8 + half * 4;
            *(unsigned long long*)(&As[buf][us]) = pk;
        }
    };
    auto compute = [&](int kt) {
        const int abuf = kt & 1, bbuf = kt % 3;
        short8_t af[2], bfr[4];
        #pragma unroll
        for (int mi = 0; mi < 2; ++mi) {
            int row = wm * 32 + mi * 16 + r;
            int us = ((u ^ (row & 3)) * GSTR) + row * 8;
            af[mi] = *(const short8_t*)(&As[abuf][us]);
        }
        #pragma unroll
        for (int ni = 0; ni < 4; ++ni) {
            int c = wn * 64 + ni * 16 + r;
            bfr[ni] = *(const short8_t*)(&Bs[bbuf][u * 1024 + c * 8]);
        }
        #pragma unroll
        for (int mi = 0; mi < 2; ++mi)
            #pragma unroll
            for (int ni = 0; ni < 4; ++ni)
                acc[mi][ni] = __builtin_amdgcn_mfma_f32_16x16x32_bf16(af[mi], bfr[ni], acc[mi][ni], 0, 0, 0);
    };

    // prologue: tile 0 staged; tile 1 in flight
    issueA(0); issueB(0, 0);
    writeA(0);                       // implicit wait on A(0)
    issueA(1); issueB(1, 1);
    asm volatile("s_waitcnt vmcnt(3) lgkmcnt(0)" ::: "memory");  // retire B(0)
    __builtin_amdgcn_sched_barrier(0);
    __builtin_amdgcn_s_barrier();
    __builtin_amdgcn_sched_barrier(0);

    // main loop: kt = 0..41 (issues up to tile 43; tiles 0..43 all k-in-bounds)
    for (int kt = 0; kt < KT1 - 3; ++kt) {
        compute(kt);
        writeA((kt + 1) & 1);        // waits A(t+1)
        issueA(kt + 2);
        issueB(kt + 2, (kt + 2) % 3);
        // outstanding: B(t+1)1 + A(t+2)2 + B(t+2)1 = 4 -> retire B(t+1)
        asm volatile("s_waitcnt vmcnt(3) lgkmcnt(0)" ::: "memory");
        __builtin_amdgcn_sched_barrier(0);
        __builtin_amdgcn_s_barrier();
        __builtin_amdgcn_sched_barrier(0);
    }
    // kt = 42: last counted iter's compute+write; then leave counted regime
    {
        compute(KT1 - 3);            // 42
        writeA((KT1 - 2) & 1);       // A(43) -> As[1]
        __syncthreads();
    }
    // stage guarded tail tile 44 (outside counted regime)
    issueA_tail();
    issueB(KT1 - 1, (KT1 - 1) % 3);  // B(44) -> Bs[2]
    writeA((KT1 - 1) & 1);           // A(44) -> As[0]
    __syncthreads();
    compute(KT1 - 2);                // 43
    compute(KT1 - 1);                // 44

    // epilogue: C layout col=lane&15, row=(lane>>4)*4+reg (raw, no dinv)
    #pragma unroll
    for (int mi = 0; mi < 2; ++mi) {
        #pragma unroll
        for (int reg = 0; reg < 4; ++reg) {
            int grow = rowBase + wm * 32 + mi * 16 + u * 4 + reg;
            if (grow < M) {
                #pragma unroll
                for (int ni = 0; ni < 4; ++ni) {
                    int gcol = wn * 64 + ni * 16 + r;
                    h[(size_t)grow * HID + gcol] = f2bf(acc[mi][ni][reg]);
                }
            }
        }
    }
}

// ---------------- self-loop insert + dinv (one thread per node) --------------
__global__ void self_dinv(int* __restrict__ cnt, int* __restrict__ csr_f,
                          float* __restrict__ dinv,
                          int* __restrict__ ovf_cnt, int2* __restrict__ ovf, int n) {
    int i = blockIdx.x * 256 + threadIdx.x;
    if (i >= n) return;
    int c = cnt[i];
    if (c < CAP) csr_f[i * CAP + c] = i;
    else { int op = atomicAdd(ovf_cnt, 1); ovf[op] = make_int2(i, i); }
    cnt[i] = c + 1;
    dinv[i] = rsqrtf((float)(c + 1));
}

// ---------------- Aggregation 1 + bias + relu + @W2 fused ----------------
__global__ __launch_bounds__(256) void agg1(const unsigned short* __restrict__ h,
                                            const int* __restrict__ cnt,
                                            const int* __restrict__ csr_f,
                                            const float* __restrict__ dinv,
                                            const float* __restrict__ b1,
                                            const float* __restrict__ W2,
                                            const int* __restrict__ ovf_cnt,
                                            const int2* __restrict__ ovf,
                                            float* __restrict__ h2s, int n) {
    __shared__ float W2s[HID * NCLS];
    for (int i = threadIdx.x; i < HID * NCLS; i += 256) W2s[i] = W2[i];
    __syncthreads();
    int wave = threadIdx.x >> 6, lane = threadIdx.x & 63;
    int v = blockIdx.x * 4 + wave;
    if (v >= n) return;
    const int fr = lane & 15, g = lane >> 4;
    int total = cnt[v];
    int inrow = min(total, CAP);
    const int base = v * CAP;
    float acc[8] = {};
    #pragma unroll 4
    for (int j = g; j < inrow; j += 4) {
        int s = csr_f[base + j];
        float ds = dinv[s];
        uint4 q = *(const uint4*)(h + (size_t)s * HID + fr * 8);
        unsigned int w[4] = {q.x, q.y, q.z, q.w};
        #pragma unroll
        for (int p = 0; p < 4; ++p) {
            acc[p * 2 + 0] += ds * u2f(w[p] << 16);          // low bf16
            acc[p * 2 + 1] += ds * u2f(w[p] & 0xffff0000u);  // high bf16
        }
    }
    if (__builtin_expect(total > CAP, 0) && g == 0) {
        int on = *ovf_cnt;
        for (int k = 0; k < on; ++k) {
            int2 pr = ovf[k];
            if (pr.x == v) {
                int s = pr.y;
                float ds = dinv[s];
                uint4 q = *(const uint4*)(h + (size_t)s * HID + fr * 8);
                unsigned int w[4] = {q.x, q.y, q.z, q.w};
                #pragma unroll
                for (int p = 0; p < 4; ++p) {
                    acc[p * 2 + 0] += ds * u2f(w[p] << 16);
                    acc[p * 2 + 1] += ds * u2f(w[p] & 0xffff0000u);
                }
            }
        }
    }
    #pragma unroll
    for (int e = 0; e < 8; ++e) {
        acc[e] += __shfl_xor(acc[e], 16, 64);
        acc[e] += __shfl_xor(acc[e], 32, 64);
    }
    float dv = dinv[v];
    float p[NCLS];
    #pragma unroll
    for (int c = 0; c < NCLS; ++c) p[c] = 0.f;
    #pragma unroll
    for (int e = 0; e < 8; ++e) {
        int f = fr * 8 + e;
        float val = fmaxf(dv * acc[e] + b1[f], 0.f);
        #pragma unroll
        for (int c = 0; c < NCLS; ++c) p[c] += val * W2s[f * NCLS + c];
    }
    #pragma unroll
    for (int off = 8; off >= 1; off >>= 1)
        #pragma unroll
        for (int c = 0; c < NCLS; ++c)
            p[c] += __shfl_xor(p[c], off, 64);
    if (lane == 0) {
        #pragma unroll
        for (int c = 0; c < NCLS; ++c) h2s[(size_t)v * 8 + c] = dv * p[c];  // pre-scaled
        h2s[(size_t)v * 8 + 7] = 0.f;
    }
}

// ---------------- Aggregation 2 + bias ----------------
__global__ __launch_bounds__(256) void agg2(const float* __restrict__ h2s,
                                            const int* __restrict__ cnt,
                                            const int* __restrict__ csr_f,
                                            const float* __restrict__ dinv,
                                            const float* __restrict__ b2,
                                            const int* __restrict__ ovf_cnt,
                                            const int2* __restrict__ ovf,
                                            float* __restrict__ out, int n) {
    int wave = threadIdx.x >> 6, lane = threadIdx.x & 63;
    int half = lane >> 5;
    int c = lane & 7, g = (lane >> 3) & 3;
    int v = blockIdx.x * 8 + wave * 2 + half;
    if (v >= n) return;
    int total = cnt[v];
    int inrow = min(total, CAP);
    const int base = v * CAP;
    float acc = 0.f;
    #pragma unroll 4
    for (int j = g; j < inrow; j += 4) {
        int s = csr_f[base + j];
        acc += h2s[(size_t)s * 8 + c];
    }
    if (__builtin_expect(total > CAP, 0) && g == 0) {
        int on = *ovf_cnt;
        for (int k = 0; k < on; ++k) {
            int2 pr = ovf[k];
            if (pr.x == v) acc += h2s[(size_t)pr.y * 8 + c];
        }
    }
    acc += __shfl_xor(acc, 8, 64);
    acc += __shfl_xor(acc, 16, 64);
    if (g == 0 && c < NCLS) out[(size_t)v * NCLS + c] = dinv[v] * acc + b2[c];
}

extern "C" void kernel_launch(void* const* d_in, const int* in_sizes, int n_in,
                              void* d_out, int out_size, void* d_ws, size_t ws_size,
                              hipStream_t stream) {
    const float* x  = (const float*)d_in[0];
    const int*   ei = (const int*)d_in[1];    // int64 in reference but JAX x64-off => int32
    const float* W1 = (const float*)d_in[2];
    const float* b1 = (const float*)d_in[3];
    const float* W2 = (const float*)d_in[4];
    const float* b2 = (const float*)d_in[5];
    float* out = (float*)d_out;

    const int N = NNODES;
    const int E = in_sizes[1] / 2;
    const int* src = ei;
    const int* dst = ei + E;
    const int GB = (N + BM - 1) / BM;         // gemm blocks (391)
    const int FB = (E + 4095) / 4096;         // fill blocks (512t x 8 edges)

    char* ws = (char*)d_ws;
    size_t off = 0;
    auto alloc = [&](size_t bytes) {
        void* p = ws + off;
        off += (bytes + 255) & ~(size_t)255;
        return p;
    };
    int*   cnt     = (int*)alloc((size_t)N * 4);
    int*   ovf_cnt = (int*)alloc(4);
    float* dinv    = (float*)alloc((size_t)N * 4);
    int*   csr_f   = (int*)alloc((size_t)N * CAP * 4);
    int2*  ovf     = (int2*)alloc((size_t)4096 * 8);
    unsigned short* W1s = (unsigned short*)alloc((size_t)KT1 * 512 * 8 * 2);
    unsigned short* h   = (unsigned short*)alloc((size_t)N * HID * 2);
    float* h2s     = (float*)alloc((size_t)N * 8 * 4);

    // zero cnt + ovf_cnt (contiguous allocations)
    hipMemsetAsync(cnt, 0, ((char*)ovf_cnt - (char*)cnt) + 256, stream);
    prep_w1<<<(KT1 * 512 + 511) / 512, 512, 0, stream>>>(W1, W1s);
    gemm_fill<<<GB + FB, 512, 0, stream>>>(x, W1s, h, N, src, dst, E,
                                           cnt, csr_f, ovf_cnt, ovf, GB);
    self_dinv<<<(N + 255) / 256, 256, 0, stream>>>(cnt, csr_f, dinv, ovf_cnt, ovf, N);
    agg1<<<(N + 3) / 4, 256, 0, stream>>>(h, cnt, csr_f, dinv, b1, W2, ovf_cnt, ovf, h2s, N);
    agg2<<<(N + 7) / 8, 256, 0, stream>>>(h2s, cnt, csr_f, dinv, b2, ovf_cnt, ovf, out, N);
}

// Round 17
// 238.531 us; speedup vs baseline: 1.0246x; 1.0140x over previous
//
#include <hip/hip_runtime.h>
#include <hip/hip_bf16.h>

typedef __attribute__((ext_vector_type(8))) short short8_t;
typedef __attribute__((ext_vector_type(4))) float f32x4;
typedef float f32x4u __attribute__((ext_vector_type(4), aligned(4)));  // 4B-aligned vector load

#define NNODES 50000
#define FIN 1433
#define HID 128
#define NCLS 7
#define KT1 45          // ceil(1433/32)
#define BK 32
#define BM 128
#define CAP 96          // fixed CSR slots/node; Poisson(32) => P(deg>96) ~ 0; exact via ovf
#define GSTR 1040       // A LDS g-stride in ushorts (128*8 + 16 pad -> conflict-free)

static __device__ __forceinline__ unsigned short f2bf(float f) {
    union { float f; unsigned int u; } v; v.f = f;
    unsigned int u = v.u;
    u += 0x7FFFu + ((u >> 16) & 1u);   // round-to-nearest-even
    return (unsigned short)(u >> 16);
}
static __device__ __forceinline__ float u2f(unsigned int u) {
    union { unsigned int u; float f; } v; v.u = u; return v.f;
}

// ---------------- W1 pack: W1[FIN][HID] f32 -> W1s[KT1][512 segs][8 bf16]
__global__ void prep_w1(const float* __restrict__ W1, unsigned short* __restrict__ W1s) {
    int tid = blockIdx.x * 512 + threadIdx.x;
    if (tid >= KT1 * 512) return;
    int kt = tid >> 9, seg = tid & 511;
    int c = seg & 127, g = seg >> 7;
    int kb = kt * BK + g * 8;
    unsigned int w[4];
    #pragma unroll
    for (int p = 0; p < 4; ++p) {
        int k0 = kb + p * 2, k1 = kb + p * 2 + 1;
        unsigned short lo = (k0 < FIN) ? f2bf(W1[(size_t)k0 * HID + c]) : (unsigned short)0;
        unsigned short hi = (k1 < FIN) ? f2bf(W1[(size_t)k1 * HID + c]) : (unsigned short)0;
        w[p] = (unsigned int)lo | ((unsigned int)hi << 16);
    }
    uint4* dstp = (uint4*)(W1s + (size_t)tid * 8);
    uint4 val; val.x = w[0]; val.y = w[1]; val.z = w[2]; val.w = w[3];
    *dstp = val;
}

// ---------------- FAT kernel: gemm blocks [0,gb) || FILL blocks [gb, grid) ---
// GEMM: BM=128, BK=32, 512t, 41KB LDS -> 3 blocks/CU. PLAIN __syncthreads()
// per K-iter (no inline-asm scaffolding -- R14-R16's spill suspect), compiler
// schedules waits natively. FILL: fixed-stride CSR scatter.
__global__ __launch_bounds__(512) void gemm_fill(const float* __restrict__ x,
                                                 const unsigned short* __restrict__ W1s,
                                                 unsigned short* __restrict__ h, int M,
                                                 const int* __restrict__ src,
                                                 const int* __restrict__ dst, int E,
                                                 int* __restrict__ cnt,
                                                 int* __restrict__ csr_f,
                                                 int* __restrict__ ovf_cnt,
                                                 int2* __restrict__ ovf, int gb) {
    __shared__ unsigned short As[2][4160];   // [g^(row&3)][row][8], GSTR=1040
    __shared__ unsigned short Bs[3][4096];   // [g 4][c 128][8] linear (gload_lds)

    if (blockIdx.x >= gb) {
        // ---- fill blocks: 512 threads x 8 edges ----
        int bid = blockIdx.x - gb;
        int i = (bid * 512 + (int)threadIdx.x) * 8;
        int lim = min(i + 8, E);
        for (int e = i; e < lim; ++e) {
            int d = dst[e], s = src[e];
            int pos = atomicAdd(&cnt[d], 1);
            if (pos < CAP) csr_f[d * CAP + pos] = s;
            else { int op = atomicAdd(ovf_cnt, 1); ovf[op] = make_int2(d, s); }
        }
        return;
    }

    // ---- gemm blocks ----
    const int t = threadIdx.x;
    const int wave = t >> 6, lane = t & 63;
    const int wm = wave >> 1, wn = wave & 1;
    const int r = lane & 15, u = lane >> 4;       // u in 0..3 = K-octet & row-quad
    const int rowBase = blockIdx.x * BM;
    f32x4 acc[2][4] = {};

    float4 areg[2];

    auto issueA = [&](int kt) {
        int k0 = kt * BK;
        #pragma unroll
        for (int i = 0; i < 2; ++i) {
            int quad = i * 512 + t;
            int row = quad >> 3, kq = quad & 7;
            int gr = min(rowBase + row, M - 1);   // clamp; OOB rows unstored
            int gk = k0 + kq * 4;                 // in-bounds for kt <= 43
            f32x4u v = *(const f32x4u*)(x + (size_t)gr * FIN + gk);
            areg[i].x = v.x; areg[i].y = v.y; areg[i].z = v.z; areg[i].w = v.w;
        }
    };
    auto issueA_tail = [&]() {                    // kt=44: k 1408..1439, guard FIN
        #pragma unroll
        for (int i = 0; i < 2; ++i) {
            int quad = i * 512 + t;
            int row = quad >> 3, kq = quad & 7;
            int gr = min(rowBase + row, M - 1);
            int gk = 1408 + kq * 4;
            const float* p = x + (size_t)gr * FIN;
            areg[i].x = (gk + 0 < FIN) ? p[gk + 0] : 0.f;
            areg[i].y = (gk + 1 < FIN) ? p[gk + 1] : 0.f;
            areg[i].z = (gk + 2 < FIN) ? p[gk + 2] : 0.f;
            areg[i].w = (gk + 3 < FIN) ? p[gk + 3] : 0.f;
        }
    };
    auto issueB = [&](int kt, int buf) {
        const unsigned short* gp = W1s + ((size_t)kt * 512 + t) * 8;
        unsigned short* lp = &Bs[buf][(wave * 64) * 8];
        __builtin_amdgcn_global_load_lds(
            (const __attribute__((address_space(1))) unsigned int*)gp,
            (__attribute__((address_space(3))) unsigned int*)lp, 16, 0, 0);
    };
    auto writeA = [&](int buf) {
        #pragma unroll
        for (int i = 0; i < 2; ++i) {
            int quad = i * 512 + t;
            int row = quad >> 3, kq = quad & 7;
            __hip_bfloat162 lo2 = __float22bfloat162_rn(make_float2(areg[i].x, areg[i].y));
            __hip_bfloat162 hi2 = __float22bfloat162_rn(make_float2(areg[i].z, areg[i].w));
            unsigned int ulo, uhi;
            __builtin_memcpy(&ulo, &lo2, 4);
            __builtin_memcpy(&uhi, &hi2, 4);
            unsigned long long pk = ((unsigned long long)uhi << 32) | (unsigned long long)ulo;
            int g = kq >> 1, half = kq & 1;
            int us = ((g ^ (row & 3)) * GSTR) + row * 8 + half * 4;
            *(unsigned long long*)(&As[buf][us]) = pk;
        }
    };
    auto compute = [&](int kt) {
        const int abuf = kt & 1, bbuf = kt % 3;
        short8_t af[2], bfr[4];
        #pragma unroll
        for (int mi = 0; mi < 2; ++mi) {
            int row = wm * 32 + mi * 16 + r;
            int us = ((u ^ (row & 3)) * GSTR) + row * 8;
            af[mi] = *(const short8_t*)(&As[abuf][us]);
        }
        #pragma unroll
        for (int ni = 0; ni < 4; ++ni) {
            int c = wn * 64 + ni * 16 + r;
            bfr[ni] = *(const short8_t*)(&Bs[bbuf][u * 1024 + c * 8]);
        }
        #pragma unroll
        for (int mi = 0; mi < 2; ++mi)
            #pragma unroll
            for (int ni = 0; ni < 4; ++ni)
                acc[mi][ni] = __builtin_amdgcn_mfma_f32_16x16x32_bf16(af[mi], bfr[ni], acc[mi][ni], 0, 0, 0);
    };

    // prologue: tile 0 staged; tile 1 in flight
    issueA(0); issueB(0, 0);
    writeA(0);                       // implicit wait on A(0)
    issueA(1); issueB(1, 1);
    __syncthreads();                 // drains B(0); A(1)/B(1) complete too (full drain)

    // main loop: kt = 0..41 (issues up to tile 43; tiles 0..43 all k-in-bounds)
    for (int kt = 0; kt < KT1 - 3; ++kt) {
        compute(kt);
        writeA((kt + 1) & 1);        // A(t+1) loads landed by prev barrier
        issueA(kt + 2);
        issueB(kt + 2, (kt + 2) % 3);
        __syncthreads();             // one barrier/iter; full drain, 3-block TLP hides it
    }
    // kt = 42
    {
        compute(KT1 - 3);            // 42
        writeA((KT1 - 2) & 1);       // A(43) -> As[1]
        __syncthreads();
    }
    // stage guarded tail tile 44
    issueA_tail();
    issueB(KT1 - 1, (KT1 - 1) % 3);  // B(44) -> Bs[2]
    writeA((KT1 - 1) & 1);           // A(44) -> As[0]
    __syncthreads();
    compute(KT1 - 2);                // 43
    compute(KT1 - 1);                // 44

    // epilogue: C layout col=lane&15, row=(lane>>4)*4+reg (raw, no dinv)
    #pragma unroll
    for (int mi = 0; mi < 2; ++mi) {
        #pragma unroll
        for (int reg = 0; reg < 4; ++reg) {
            int grow = rowBase + wm * 32 + mi * 16 + u * 4 + reg;
            if (grow < M) {
                #pragma unroll
                for (int ni = 0; ni < 4; ++ni) {
                    int gcol = wn * 64 + ni * 16 + r;
                    h[(size_t)grow * HID + gcol] = f2bf(acc[mi][ni][reg]);
                }
            }
        }
    }
}

// ---------------- self-loop insert + dinv (one thread per node) --------------
__global__ void self_dinv(int* __restrict__ cnt, int* __restrict__ csr_f,
                          float* __restrict__ dinv,
                          int* __restrict__ ovf_cnt, int2* __restrict__ ovf, int n) {
    int i = blockIdx.x * 256 + threadIdx.x;
    if (i >= n) return;
    int c = cnt[i];
    if (c < CAP) csr_f[i * CAP + c] = i;
    else { int op = atomicAdd(ovf_cnt, 1); ovf[op] = make_int2(i, i); }
    cnt[i] = c + 1;
    dinv[i] = rsqrtf((float)(c + 1));
}

// ---------------- Aggregation 1 + bias + relu + @W2 fused ----------------
__global__ __launch_bounds__(256) void agg1(const unsigned short* __restrict__ h,
                                            const int* __restrict__ cnt,
                                            const int* __restrict__ csr_f,
                                            const float* __restrict__ dinv,
                                            const float* __restrict__ b1,
                                            const float* __restrict__ W2,
                                            const int* __restrict__ ovf_cnt,
                                            const int2* __restrict__ ovf,
                                            float* __restrict__ h2s, int n) {
    __shared__ float W2s[HID * NCLS];
    for (int i = threadIdx.x; i < HID * NCLS; i += 256) W2s[i] = W2[i];
    __syncthreads();
    int wave = threadIdx.x >> 6, lane = threadIdx.x & 63;
    int v = blockIdx.x * 4 + wave;
    if (v >= n) return;
    const int fr = lane & 15, g = lane >> 4;
    int total = cnt[v];
    int inrow = min(total, CAP);
    const int base = v * CAP;
    float acc[8] = {};
    #pragma unroll 4
    for (int j = g; j < inrow; j += 4) {
        int s = csr_f[base + j];
        float ds = dinv[s];
        uint4 q = *(const uint4*)(h + (size_t)s * HID + fr * 8);
        unsigned int w[4] = {q.x, q.y, q.z, q.w};
        #pragma unroll
        for (int p = 0; p < 4; ++p) {
            acc[p * 2 + 0] += ds * u2f(w[p] << 16);          // low bf16
            acc[p * 2 + 1] += ds * u2f(w[p] & 0xffff0000u);  // high bf16
        }
    }
    if (__builtin_expect(total > CAP, 0) && g == 0) {
        int on = *ovf_cnt;
        for (int k = 0; k < on; ++k) {
            int2 pr = ovf[k];
            if (pr.x == v) {
                int s = pr.y;
                float ds = dinv[s];
                uint4 q = *(const uint4*)(h + (size_t)s * HID + fr * 8);
                unsigned int w[4] = {q.x, q.y, q.z, q.w};
                #pragma unroll
                for (int p = 0; p < 4; ++p) {
                    acc[p * 2 + 0] += ds * u2f(w[p] << 16);
                    acc[p * 2 + 1] += ds * u2f(w[p] & 0xffff0000u);
                }
            }
        }
    }
    #pragma unroll
    for (int e = 0; e < 8; ++e) {
        acc[e] += __shfl_xor(acc[e], 16, 64);
        acc[e] += __shfl_xor(acc[e], 32, 64);
    }
    float dv = dinv[v];
    float p[NCLS];
    #pragma unroll
    for (int c = 0; c < NCLS; ++c) p[c] = 0.f;
    #pragma unroll
    for (int e = 0; e < 8; ++e) {
        int f = fr * 8 + e;
        float val = fmaxf(dv * acc[e] + b1[f], 0.f);
        #pragma unroll
        for (int c = 0; c < NCLS; ++c) p[c] += val * W2s[f * NCLS + c];
    }
    #pragma unroll
    for (int off = 8; off >= 1; off >>= 1)
        #pragma unroll
        for (int c = 0; c < NCLS; ++c)
            p[c] += __shfl_xor(p[c], off, 64);
    if (lane == 0) {
        #pragma unroll
        for (int c = 0; c < NCLS; ++c) h2s[(size_t)v * 8 + c] = dv * p[c];  // pre-scaled
        h2s[(size_t)v * 8 + 7] = 0.f;
    }
}

// ---------------- Aggregation 2 + bias ----------------
__global__ __launch_bounds__(256) void agg2(const float* __restrict__ h2s,
                                            const int* __restrict__ cnt,
                                            const int* __restrict__ csr_f,
                                            const float* __restrict__ dinv,
                                            const float* __restrict__ b2,
                                            const int* __restrict__ ovf_cnt,
                                            const int2* __restrict__ ovf,
                                            float* __restrict__ out, int n) {
    int wave = threadIdx.x >> 6, lane = threadIdx.x & 63;
    int half = lane >> 5;
    int c = lane & 7, g = (lane >> 3) & 3;
    int v = blockIdx.x * 8 + wave * 2 + half;
    if (v >= n) return;
    int total = cnt[v];
    int inrow = min(total, CAP);
    const int base = v * CAP;
    float acc = 0.f;
    #pragma unroll 4
    for (int j = g; j < inrow; j += 4) {
        int s = csr_f[base + j];
        acc += h2s[(size_t)s * 8 + c];
    }
    if (__builtin_expect(total > CAP, 0) && g == 0) {
        int on = *ovf_cnt;
        for (int k = 0; k < on; ++k) {
            int2 pr = ovf[k];
            if (pr.x == v) acc += h2s[(size_t)pr.y * 8 + c];
        }
    }
    acc += __shfl_xor(acc, 8, 64);
    acc += __shfl_xor(acc, 16, 64);
    if (g == 0 && c < NCLS) out[(size_t)v * NCLS + c] = dinv[v] * acc + b2[c];
}

extern "C" void kernel_launch(void* const* d_in, const int* in_sizes, int n_in,
                              void* d_out, int out_size, void* d_ws, size_t ws_size,
                              hipStream_t stream) {
    const float* x  = (const float*)d_in[0];
    const int*   ei = (const int*)d_in[1];    // int64 in reference but JAX x64-off => int32
    const float* W1 = (const float*)d_in[2];
    const float* b1 = (const float*)d_in[3];
    const float* W2 = (const float*)d_in[4];
    const float* b2 = (const float*)d_in[5];
    float* out = (float*)d_out;

    const int N = NNODES;
    const int E = in_sizes[1] / 2;
    const int* src = ei;
    const int* dst = ei + E;
    const int GB = (N + BM - 1) / BM;         // gemm blocks (391)
    const int FB = (E + 4095) / 4096;         // fill blocks (512t x 8 edges)

    char* ws = (char*)d_ws;
    size_t off = 0;
    auto alloc = [&](size_t bytes) {
        void* p = ws + off;
        off += (bytes + 255) & ~(size_t)255;
        return p;
    };
    int*   cnt     = (int*)alloc((size_t)N * 4);
    int*   ovf_cnt = (int*)alloc(4);
    float* dinv    = (float*)alloc((size_t)N * 4);
    int*   csr_f   = (int*)alloc((size_t)N * CAP * 4);
    int2*  ovf     = (int2*)alloc((size_t)4096 * 8);
    unsigned short* W1s = (unsigned short*)alloc((size_t)KT1 * 512 * 8 * 2);
    unsigned short* h   = (unsigned short*)alloc((size_t)N * HID * 2);
    float* h2s     = (float*)alloc((size_t)N * 8 * 4);

    // zero cnt + ovf_cnt (contiguous allocations)
    hipMemsetAsync(cnt, 0, ((char*)ovf_cnt - (char*)cnt) + 256, stream);
    prep_w1<<<(KT1 * 512 + 511) / 512, 512, 0, stream>>>(W1, W1s);
    gemm_fill<<<GB + FB, 512, 0, stream>>>(x, W1s, h, N, src, dst, E,
                                           cnt, csr_f, ovf_cnt, ovf, GB);
    self_dinv<<<(N + 255) / 256, 256, 0, stream>>>(cnt, csr_f, dinv, ovf_cnt, ovf, N);
    agg1<<<(N + 3) / 4, 256, 0, stream>>>(h, cnt, csr_f, dinv, b1, W2, ovf_cnt, ovf, h2s, N);
    agg2<<<(N + 7) / 8, 256, 0, stream>>>(h2s, cnt, csr_f, dinv, b2, ovf_cnt, ovf, out, N);
}